// Round 4
// baseline (647.126 us; speedup 1.0000x reference)
//
#include <hip/hip_runtime.h>
#include <math.h>

// SuperVoxel critical-component loss on MI355X.
// mean( (0.5 + 0.25*neg + 0.25*pos) * bce_loss )
// Two-level CCL: per-tile union-find in LDS (64x64 tiles) with per-local-root
// mistake flags computed in LDS; global union only on tile-boundary edges;
// flag resolution over the sparse local-root LIST (flagup/flagdown), never
// per-pixel; fused vectorized loss accumulation into per-block partials.

#define HH 1024
#define WW 1024
#define IMGPIX (HH * WW)
#define NB_TOTAL 16
#define FLAGBIT 0x40000000
#define IDXMASK 0x3FFFFFFF
#define NBLK 2048
#define NTHR 256
#define TSZ 64
#define TILES_X (WW / TSZ)                    // 16
#define TILES_PER_IMG (TILES_X * (HH / TSZ))  // 256
#define WPI (IMGPIX / 64)                     // mask words per image: 16384
#define MAXR 2048                             // hard max local roots per 64x64 tile

typedef unsigned long long u64;

// ---------- global union-find (entries may carry FLAGBIT; always mask) ------
__device__ __forceinline__ int findRootG(const int* __restrict__ p, int i) {
    int r = i;
    int pr = p[r] & IDXMASK;
    while (pr != r) { r = pr; pr = p[r] & IDXMASK; }
    return r;
}

__device__ __forceinline__ void uniteG(int* p, int a, int b) {
    int ra = findRootG(p, a);
    int rb = findRootG(p, b);
    while (ra != rb) {
        if (ra < rb) { int t = ra; ra = rb; rb = t; }  // hook larger under smaller
        int prev = atomicCAS(&p[ra], ra, rb);
        if (prev == ra) return;
        ra = findRootG(p, prev & IDXMASK);
        rb = findRootG(p, rb);
    }
}

// ---------- LDS union-find (entries may carry FLAGBIT in flag pass) ---------
__device__ __forceinline__ int findRootL(volatile int* lab, int i) {
    int r = i;
    int e = lab[r] & IDXMASK;
    while (e != r) { r = e; e = lab[r] & IDXMASK; }
    return r;
}

__device__ __forceinline__ void uniteL(int* lab, int a, int b) {
    volatile int* vl = lab;
    int ra = findRootL(vl, a);
    int rb = findRootL(vl, b);
    while (ra != rb) {
        if (ra < rb) { int t = ra; ra = rb; rb = t; }
        int prev = atomicCAS(&lab[ra], ra, rb);
        if (prev == ra) return;
        ra = findRootL(vl, prev & IDXMASK);
        rb = findRootL(vl, rb);
    }
}

__global__ void k_zero(double* __restrict__ part) {
    part[blockIdx.x * blockDim.x + threadIdx.x] = 0.0;
}

// One block = one 64x64 tile; loads preds+targets once, ballots both masks,
// then runs both phases' local CCL in LDS. Writes: masks, parent arrays
// (pixel -> tile-local root), per-tile compacted local-root list with flags.
__global__ void k_local(const float* __restrict__ preds, const float* __restrict__ targets,
                        long gbase, u64* __restrict__ mP, u64* __restrict__ mT,
                        int* __restrict__ parentP, int* __restrict__ parentT,
                        int* __restrict__ lists, int* __restrict__ counts, int ntiles) {
    __shared__ int lab[TSZ * TSZ];
    __shared__ u64 rowmT[TSZ];
    __shared__ u64 rowmP[TSZ];
    __shared__ int llist[MAXR];
    __shared__ int lcnt;

    const int img = blockIdx.x / TILES_PER_IMG;
    const int tile = blockIdx.x % TILES_PER_IMG;
    const int ty = tile / TILES_X, tx = tile % TILES_X;
    const int w = threadIdx.x >> 6, lane = threadIdx.x & 63;
    const int imgpix = img * IMGPIX;
    const int tilebase = (ty * TSZ) * WW + tx * TSZ;

    // load both inputs once, ballot both masks
    #pragma unroll 4
    for (int j = 0; j < 16; ++j) {
        int r = w * 16 + j;
        long g = gbase + imgpix + tilebase + (long)r * WW + lane;
        float p = preds[g];
        float t = targets[g];
        u64 bp = __ballot(p > 0.5f);
        u64 bt = __ballot(t > 0.0f);
        if (lane == 0) {
            rowmP[r] = bp; rowmT[r] = bt;
            int wi = img * WPI + (ty * TSZ + r) * TILES_X + tx;
            mP[wi] = bp; mT[wi] = bt;
        }
    }
    __syncthreads();

    for (int ph = 0; ph < 2; ++ph) {
        const u64* rowm = ph ? rowmP : rowmT;   // component mask
        const u64* other = ph ? rowmT : rowmP;  // coverage mask (mistake = fg && !other)
        int* parent = ph ? parentP : parentT;

        if (threadIdx.x == 0) lcnt = 0;

        // init: left-chains within rows
        #pragma unroll 4
        for (int j = 0; j < 16; ++j) {
            int r = w * 16 + j;
            int li = r * TSZ + lane;
            u64 m = rowm[r];
            int par = li;
            if (((m >> lane) & 1) && lane > 0 && ((m >> (lane - 1)) & 1)) par = li - 1;
            lab[li] = par;
        }
        __syncthreads();

        // vertical unions (dedup via left column pair)
        #pragma unroll 4
        for (int j = 0; j < 16; ++j) {
            int r = w * 16 + j;
            if (r >= TSZ - 1) continue;
            u64 m0 = rowm[r], m1 = rowm[r + 1];
            if (((m0 >> lane) & 1) && ((m1 >> lane) & 1)) {
                bool skip = (lane > 0) && ((m0 >> (lane - 1)) & 1) && ((m1 >> (lane - 1)) & 1);
                if (!skip) uniteL(lab, r * TSZ + lane, (r + 1) * TSZ + lane);
            }
        }
        __syncthreads();

        // pass A: find local root, write parent entry, OR mistake flag onto root
        #pragma unroll 4
        for (int j = 0; j < 16; ++j) {
            int r = w * 16 + j;
            int li = r * TSZ + lane;
            int self = imgpix + tilebase + r * WW + lane;
            int gp = self;
            if ((rowm[r] >> lane) & 1) {
                int rt = findRootL(lab, li);
                gp = imgpix + tilebase + (rt >> 6) * WW + (rt & 63);
                if (!((other[r] >> lane) & 1)) atomicOr(&lab[rt], FLAGBIT);
            }
            parent[self] = gp;
        }
        __syncthreads();

        // pass B: local roots push (global_idx | flag) to LDS list
        #pragma unroll 4
        for (int j = 0; j < 16; ++j) {
            int r = w * 16 + j;
            int li = r * TSZ + lane;
            if (((rowm[r] >> lane) & 1) && (lab[li] & IDXMASK) == li) {
                int slot = atomicAdd(&lcnt, 1);
                llist[slot] = (imgpix + tilebase + r * WW + lane) | (lab[li] & FLAGBIT);
            }
        }
        __syncthreads();

        // pass C: copy list to the tile's fixed global region
        if (threadIdx.x == 0) counts[ph * ntiles + blockIdx.x] = lcnt;
        for (int s = threadIdx.x; s < lcnt; s += NTHR)
            lists[((size_t)ph * ntiles + blockIdx.x) * MAXR + s] = llist[s];
        __syncthreads();  // lab/lcnt reused next phase
    }
}

// Global unions across tile boundaries only.
__global__ void k_boundary(const u64* __restrict__ mP, const u64* __restrict__ mT,
                           int* __restrict__ parentP, int* __restrict__ parentT,
                           int nb) {
    const int per_img = 2 * 15 * WW;  // 30720
    long total = (long)nb * per_img * 2;
    long stride = (long)gridDim.x * blockDim.x;
    for (long e = blockIdx.x * (long)blockDim.x + threadIdx.x; e < total; e += stride) {
        int ph = (int)(e & 1);
        long e2 = e >> 1;
        int img = (int)(e2 / per_img);
        int k = (int)(e2 % per_img);
        int a, b;
        if (k < 15 * WW) {            // horizontal cut: y = 64c+63
            int cut = k >> 10, x = k & (WW - 1);
            a = (cut * TSZ + 63) * WW + x;
            b = a + WW;
        } else {                      // vertical cut: x = 64c+63
            int k2 = k - 15 * WW;
            int cut = k2 >> 10, y = k2 & (HH - 1);
            a = y * WW + cut * TSZ + 63;
            b = a + 1;
        }
        const u64* m = ph ? mP : mT;
        int* parent = ph ? parentP : parentT;
        long wbase = (long)img * WPI;
        bool fa = (m[wbase + (a >> 6)] >> (a & 63)) & 1;
        bool fb = (m[wbase + (b >> 6)] >> (b & 63)) & 1;
        if (fa && fb) uniteG(parent, img * IMGPIX + a, img * IMGPIX + b);
    }
}

// For each FLAGGED local root in the lists: OR FLAGBIT onto its global root.
__global__ void k_flagup(const int* __restrict__ counts, const int* __restrict__ lists,
                         int* __restrict__ parentT, int* __restrict__ parentP, int ntiles) {
    long total = 2L * ntiles * MAXR;
    long stride = (long)gridDim.x * blockDim.x;
    for (long s = blockIdx.x * (long)blockDim.x + threadIdx.x; s < total; s += stride) {
        int ph = (int)(s / ((long)ntiles * MAXR));
        long r = s % ((long)ntiles * MAXR);
        int tile = (int)(r >> 11), slot = (int)(r & (MAXR - 1));
        if (slot >= counts[ph * ntiles + tile]) continue;
        int e = lists[((size_t)ph * ntiles + tile) * MAXR + slot];
        if (!(e & FLAGBIT)) continue;
        int* parent = ph ? parentP : parentT;
        int rt = findRootG(parent, e & IDXMASK);
        if (!(parent[rt] & FLAGBIT)) atomicOr(&parent[rt], FLAGBIT);
    }
}

// For each local root: copy global root's flag onto the local root's entry.
__global__ void k_flagdown(const int* __restrict__ counts, const int* __restrict__ lists,
                           int* __restrict__ parentT, int* __restrict__ parentP, int ntiles) {
    long total = 2L * ntiles * MAXR;
    long stride = (long)gridDim.x * blockDim.x;
    for (long s = blockIdx.x * (long)blockDim.x + threadIdx.x; s < total; s += stride) {
        int ph = (int)(s / ((long)ntiles * MAXR));
        long r = s % ((long)ntiles * MAXR);
        int tile = (int)(r >> 11), slot = (int)(r & (MAXR - 1));
        if (slot >= counts[ph * ntiles + tile]) continue;
        int idx = lists[((size_t)ph * ntiles + tile) * MAXR + slot] & IDXMASK;
        int* parent = ph ? parentP : parentT;
        int rt = findRootG(parent, idx);
        if (parent[rt] & FLAGBIT) {
            int e2 = parent[idx];
            if (!(e2 & FLAGBIT)) parent[idx] = e2 | FLAGBIT;
        }
    }
}

// Fused loss + both weight terms, vectorized x4, per-block partials.
__global__ void k_accum(const int* __restrict__ parentT, const int* __restrict__ parentP,
                        const float* __restrict__ preds, const float* __restrict__ targets,
                        long gbase, int n, double* __restrict__ part) {
    int stride = gridDim.x * blockDim.x;
    double local = 0.0;
    int nv = n >> 2;
    const float4* p4 = (const float4*)(preds + gbase);
    const float4* t4 = (const float4*)(targets + gbase);
    const int4* pt4 = (const int4*)parentT;
    const int4* pp4 = (const int4*)parentP;
    for (int i = blockIdx.x * blockDim.x + threadIdx.x; i < nv; i += stride) {
        float4 p = p4[i];
        float4 t = t4[i];
        int4 rT = pt4[i];
        int4 rP = pp4[i];
        float pp[4] = {p.x, p.y, p.z, p.w};
        float tt[4] = {t.x, t.y, t.z, t.w};
        int rt[4] = {rT.x, rT.y, rT.z, rT.w};
        int rp[4] = {rP.x, rP.y, rP.z, rP.w};
        #pragma unroll
        for (int j = 0; j < 4; ++j) {
            float pv = pp[j], tv = tt[j];
            float loss = fmaxf(pv, 0.0f) - pv * tv + log1pf(__expf(-fabsf(pv)));
            float wgt = 0.5f;
            if (tv > 0.0f) {
                if (parentT[rt[j] & IDXMASK] & FLAGBIT) wgt += 0.25f;
            }
            if (pv > 0.5f) {
                if (parentP[rp[j] & IDXMASK] & FLAGBIT) wgt += 0.25f;
            }
            local += (double)(wgt * loss);
        }
    }
    #pragma unroll
    for (int off = 32; off > 0; off >>= 1) local += __shfl_down(local, off, 64);
    __shared__ double s[NTHR / 64];
    int lane = threadIdx.x & 63, wid = threadIdx.x >> 6;
    if (lane == 0) s[wid] = local;
    __syncthreads();
    if (threadIdx.x == 0) {
        double tot = 0.0;
        #pragma unroll
        for (int w = 0; w < NTHR / 64; ++w) tot += s[w];
        part[blockIdx.x] += tot;  // zeroed each call; chunks accumulate serially
    }
}

__global__ void k_final(const double* __restrict__ part, float* __restrict__ out, double inv_n) {
    double v = 0.0;
    for (int i = threadIdx.x; i < NBLK; i += blockDim.x) v += part[i];
    #pragma unroll
    for (int off = 32; off > 0; off >>= 1) v += __shfl_down(v, off, 64);
    __shared__ double s[NTHR / 64];
    int lane = threadIdx.x & 63, wid = threadIdx.x >> 6;
    if (lane == 0) s[wid] = v;
    __syncthreads();
    if (threadIdx.x == 0) {
        double tot = 0.0;
        #pragma unroll
        for (int w = 0; w < NTHR / 64; ++w) tot += s[w];
        out[0] = (float)(tot * inv_n);
    }
}

extern "C" void kernel_launch(void* const* d_in, const int* in_sizes, int n_in,
                              void* d_out, int out_size, void* d_ws, size_t ws_size,
                              hipStream_t stream) {
    const float* preds = (const float*)d_in[0];
    const float* targets = (const float*)d_in[1];
    float* out = (float*)d_out;

    // ws: partials | maskT | maskP | parentT | parentP | counts | lists  (chunked)
    double* part = (double*)d_ws;
    char* base = (char*)d_ws + NBLK * sizeof(double);
    size_t avail = (ws_size > NBLK * sizeof(double)) ? ws_size - NBLK * sizeof(double) : 0;
    const size_t per_img = 2 * WPI * sizeof(u64)
                         + 2 * (size_t)IMGPIX * sizeof(int)
                         + 2 * TILES_PER_IMG * sizeof(int)
                         + 2 * (size_t)TILES_PER_IMG * MAXR * sizeof(int);
    int chunk = (int)(avail / per_img);
    if (chunk < 1) chunk = 1;
    if (chunk > NB_TOTAL) chunk = NB_TOTAL;

    u64* mT = (u64*)base;
    u64* mP = mT + (size_t)chunk * WPI;
    int* parentT = (int*)(mP + (size_t)chunk * WPI);
    int* parentP = parentT + (size_t)chunk * IMGPIX;
    int* counts = parentP + (size_t)chunk * IMGPIX;
    int* lists = counts + 2 * (size_t)chunk * TILES_PER_IMG;

    k_zero<<<NBLK / NTHR, NTHR, 0, stream>>>(part);

    for (int b0 = 0; b0 < NB_TOTAL; b0 += chunk) {
        int nb = (b0 + chunk <= NB_TOTAL) ? chunk : (NB_TOTAL - b0);
        int n = nb * IMGPIX;
        long gbase = (long)b0 * IMGPIX;
        int ntiles = nb * TILES_PER_IMG;

        k_local<<<ntiles, NTHR, 0, stream>>>(preds, targets, gbase, mP, mT,
                                             parentP, parentT, lists, counts, ntiles);
        k_boundary<<<512, NTHR, 0, stream>>>(mP, mT, parentP, parentT, nb);
        k_flagup<<<NBLK, NTHR, 0, stream>>>(counts, lists, parentT, parentP, ntiles);
        k_flagdown<<<NBLK, NTHR, 0, stream>>>(counts, lists, parentT, parentP, ntiles);
        k_accum<<<NBLK, NTHR, 0, stream>>>(parentT, parentP, preds, targets, gbase, n, part);
    }

    double inv_n = 1.0 / ((double)NB_TOTAL * (double)IMGPIX);
    k_final<<<1, NTHR, 0, stream>>>(part, out, inv_n);
}

// Round 5
// 579.887 us; speedup vs baseline: 1.1160x; 1.1160x over previous
//
#include <hip/hip_runtime.h>
#include <math.h>

// SuperVoxel critical-component loss on MI355X.
// mean( (0.5 + 0.25*neg + 0.25*pos) * bce_loss )
// Run-based CCL: union-find over horizontal RUNS (not pixels). Run id is pure
// bit math from row bitmasks (no per-pixel label array). Flags OR'd onto run
// roots; compress makes every run entry = root|flag; fused loss accumulation
// looks up criticality once per run segment.

#define HH 1024
#define WW 1024
#define IMGPIX (HH * WW)
#define NB_TOTAL 16
#define FLAGBIT 0x40000000
#define IDXMASK 0x3FFFFFFF
#define NBLK 2048
#define NTHR 256
#define RPR 512        // run slots per row (hard worst case: alternating pixels)
#define WPR 16         // u64 mask words per row

typedef unsigned long long u64;

__device__ __forceinline__ int findRootG(const int* __restrict__ p, int i) {
    int r = i;
    int pr = p[r] & IDXMASK;
    while (pr != r) { r = pr; pr = p[r] & IDXMASK; }
    return r;
}

__device__ __forceinline__ void uniteG(int* p, int a, int b) {
    int ra = findRootG(p, a), rb = findRootG(p, b);
    while (ra != rb) {
        if (ra < rb) { int t = ra; ra = rb; rb = t; }  // hook larger under smaller
        int prev = atomicCAS(&p[ra], ra, rb);
        if (prev == ra) return;
        ra = findRootG(p, prev & IDXMASK);
        rb = findRootG(p, rb);
    }
}

// run index within row of the run containing bit b (b's fg bit must be set):
// prefix = #starts in earlier words; (2<<63)-1 wraps to ~0 so b=63 works.
__device__ __forceinline__ int runIndex(u64 starts, int prefix, int b) {
    u64 below = (2ULL << b) - 1ULL;
    return prefix + (int)__popcll(starts & below) - 1;
}

__global__ void k_zero(double* __restrict__ part) {
    part[blockIdx.x * blockDim.x + threadIdx.x] = 0.0;
}

// Ballot fg masks for both phases + init both parent arrays.
__global__ void k_maskinit(const float* __restrict__ preds, const float* __restrict__ targets,
                           long gbase, int npx, u64* __restrict__ fT, u64* __restrict__ fP,
                           int* __restrict__ parentT, int* __restrict__ parentP, int ninit) {
    int stride = gridDim.x * blockDim.x;
    int tid = blockIdx.x * blockDim.x + threadIdx.x;
    for (int i = tid; i < npx; i += stride) {
        float p = preds[gbase + i];
        float t = targets[gbase + i];
        u64 bp = __ballot(p > 0.5f);
        u64 bt = __ballot(t > 0.0f);
        if ((i & 63) == 0) { fP[i >> 6] = bp; fT[i >> 6] = bt; }
    }
    for (int i = tid; i < ninit; i += stride) { parentT[i] = i; parentP[i] = i; }
}

// Per row: run-start masks (word-carry aware) + per-word cumulative start count.
__global__ void k_rows(const u64* __restrict__ fT, const u64* __restrict__ fP,
                       u64* __restrict__ sT, u64* __restrict__ sP,
                       int* __restrict__ prT, int* __restrict__ prP, int nrows) {
    int R = blockIdx.x * blockDim.x + threadIdx.x;
    if (R >= nrows) return;
    for (int ph = 0; ph < 2; ++ph) {
        const u64* f = ph ? fP : fT;
        u64* s = ph ? sP : sT;
        int* pr = ph ? prP : prT;
        int cum = 0;
        u64 carry = 0;
        #pragma unroll
        for (int w = 0; w < WPR; ++w) {
            u64 fw = f[R * WPR + w];
            u64 st = fw & ~((fw << 1) | carry);
            carry = fw >> 63;
            s[R * WPR + w] = st;
            pr[R * WPR + w] = cum;
            cum += (int)__popcll(st);
        }
    }
}

// One unite per vertical overlap-run between adjacent rows (per word; word-
// boundary duplicates are harmless re-unites of the same pair).
__global__ void k_link(const u64* __restrict__ fT, const u64* __restrict__ fP,
                       const u64* __restrict__ sT, const u64* __restrict__ sP,
                       const int* __restrict__ prT, const int* __restrict__ prP,
                       int* __restrict__ parentT, int* __restrict__ parentP, int nrows) {
    int id = blockIdx.x * blockDim.x + threadIdx.x;
    int per = nrows * WPR;
    if (id >= 2 * per) return;
    int ph = id >= per;
    int rem = ph ? id - per : id;
    int R = rem >> 4, w = rem & 15;
    if ((R & (HH - 1)) == HH - 1) return;  // no link across image boundary
    const u64* f = ph ? fP : fT;
    const u64* s = ph ? sP : sT;
    const int* pr = ph ? prP : prT;
    int* parent = ph ? parentP : parentT;
    int w0 = R * WPR + w, w1 = w0 + WPR;
    u64 f0 = f[w0], f1 = f[w1];
    u64 o = f0 & f1;
    if (!o) return;
    u64 s0 = s[w0], s1 = s[w1];
    int p0 = pr[w0], p1 = pr[w1];
    int base0 = R * RPR, base1 = base0 + RPR;
    u64 os = o & ~(o << 1);  // overlap-run starts (one unite each)
    while (os) {
        int b = __builtin_ctzll(os);
        os &= os - 1;
        uniteG(parent, base0 + runIndex(s0, p0, b), base1 + runIndex(s1, p1, b));
    }
}

// For each run containing a mistake pixel (fgA & !fgB): flag its root.
__global__ void k_flagup(const u64* __restrict__ fT, const u64* __restrict__ fP,
                         const u64* __restrict__ sT, const u64* __restrict__ sP,
                         const int* __restrict__ prT, const int* __restrict__ prP,
                         int* __restrict__ parentT, int* __restrict__ parentP, int nrows) {
    int id = blockIdx.x * blockDim.x + threadIdx.x;
    int per = nrows * WPR;
    if (id >= 2 * per) return;
    int ph = id >= per;
    int rem = ph ? id - per : id;
    int R = rem >> 4, w = rem & 15;
    const u64* fA = ph ? fP : fT;
    const u64* fB = ph ? fT : fP;
    const u64* s = ph ? sP : sT;
    const int* pr = ph ? prP : prT;
    int* parent = ph ? parentP : parentT;
    int widx = R * WPR + w;
    u64 m = fA[widx] & ~fB[widx];
    if (!m) return;
    u64 sw = s[widx];
    int pw = pr[widx];
    int base = R * RPR;
    u64 ms = m & ~(m << 1);  // mistake-run starts
    int last = -1;
    while (ms) {
        int b = __builtin_ctzll(ms);
        ms &= ms - 1;
        int rid = base + runIndex(sw, pw, b);
        if (rid != last) {  // consecutive mistake-runs in same fg-run dedup
            last = rid;
            int rt = findRootG(parent, rid);
            if (!(parent[rt] & FLAGBIT)) atomicOr(&parent[rt], FLAGBIT);
        }
    }
}

// Every run entry -> root | rootflag (1-hop lookups in accum).
__global__ void k_compress(int* __restrict__ parentT, int* __restrict__ parentP, int n) {
    int stride = gridDim.x * blockDim.x;
    for (int i = blockIdx.x * blockDim.x + threadIdx.x; i < n; i += stride) {
        int r = findRootG(parentT, i);
        parentT[i] = r | (parentT[r] & FLAGBIT);
        r = findRootG(parentP, i);
        parentP[i] = r | (parentP[r] & FLAGBIT);
    }
}

// Fused loss + weights; crit lookup once per run segment; per-block partials.
__global__ void k_accum(const float* __restrict__ preds, const float* __restrict__ targets,
                        long gbase, int npx4,
                        const u64* __restrict__ fT, const u64* __restrict__ fP,
                        const u64* __restrict__ sT, const u64* __restrict__ sP,
                        const int* __restrict__ prT, const int* __restrict__ prP,
                        const int* __restrict__ parentT, const int* __restrict__ parentP,
                        double* __restrict__ part) {
    int stride = gridDim.x * blockDim.x;
    double local = 0.0;
    const float4* p4 = (const float4*)(preds + gbase);
    const float4* t4 = (const float4*)(targets + gbase);
    for (int i = blockIdx.x * blockDim.x + threadIdx.x; i < npx4; i += stride) {
        float4 pv = p4[i];
        float4 tv = t4[i];
        int px = i << 2;
        int wi = px >> 6;
        int base = (px >> 10) * RPR;
        u64 ft = fT[wi], fp = fP[wi];
        u64 st = sT[wi], sp = sP[wi];
        int pt = prT[wi], pp = prP[wi];
        float pa[4] = {pv.x, pv.y, pv.z, pv.w};
        float ta[4] = {tv.x, tv.y, tv.z, tv.w};
        int lastT = -1, lastP = -1;
        float flagT = 0.0f, flagP = 0.0f;
        #pragma unroll
        for (int j = 0; j < 4; ++j) {
            int b = (px & 63) + j;
            float p = pa[j], t = ta[j];
            float loss = fmaxf(p, 0.0f) - p * t + log1pf(__expf(-fabsf(p)));
            float wgt = 0.5f;
            if ((ft >> b) & 1) {
                int rid = base + runIndex(st, pt, b);
                if (rid != lastT) { lastT = rid; flagT = (parentT[rid] & FLAGBIT) ? 0.25f : 0.0f; }
                wgt += flagT;
            }
            if ((fp >> b) & 1) {
                int rid = base + runIndex(sp, pp, b);
                if (rid != lastP) { lastP = rid; flagP = (parentP[rid] & FLAGBIT) ? 0.25f : 0.0f; }
                wgt += flagP;
            }
            local += (double)(wgt * loss);
        }
    }
    #pragma unroll
    for (int off = 32; off > 0; off >>= 1) local += __shfl_down(local, off, 64);
    __shared__ double sh[NTHR / 64];
    int lane = threadIdx.x & 63, wid = threadIdx.x >> 6;
    if (lane == 0) sh[wid] = local;
    __syncthreads();
    if (threadIdx.x == 0) {
        double tot = 0.0;
        #pragma unroll
        for (int w = 0; w < NTHR / 64; ++w) tot += sh[w];
        part[blockIdx.x] += tot;  // zeroed each launch; chunks accumulate serially
    }
}

__global__ void k_final(const double* __restrict__ part, float* __restrict__ out, double inv_n) {
    double v = 0.0;
    for (int i = threadIdx.x; i < NBLK; i += blockDim.x) v += part[i];
    #pragma unroll
    for (int off = 32; off > 0; off >>= 1) v += __shfl_down(v, off, 64);
    __shared__ double sh[NTHR / 64];
    int lane = threadIdx.x & 63, wid = threadIdx.x >> 6;
    if (lane == 0) sh[wid] = v;
    __syncthreads();
    if (threadIdx.x == 0) {
        double tot = 0.0;
        #pragma unroll
        for (int w = 0; w < NTHR / 64; ++w) tot += sh[w];
        out[0] = (float)(tot * inv_n);
    }
}

extern "C" void kernel_launch(void* const* d_in, const int* in_sizes, int n_in,
                              void* d_out, int out_size, void* d_ws, size_t ws_size,
                              hipStream_t stream) {
    const float* preds = (const float*)d_in[0];
    const float* targets = (const float*)d_in[1];
    float* out = (float*)d_out;

    // ws: part | fT fP | sT sP | prT prP | parentT parentP   (chunked by image)
    double* part = (double*)d_ws;
    char* base = (char*)d_ws + NBLK * sizeof(double);
    size_t avail = (ws_size > NBLK * sizeof(double)) ? ws_size - NBLK * sizeof(double) : 0;
    const size_t wpi = (size_t)HH * WPR;            // 16384 words per image
    const size_t runs_pi = (size_t)HH * RPR;        // 524288 run slots per image
    const size_t per_img = 4 * wpi * sizeof(u64) + 2 * wpi * sizeof(int)
                         + 2 * runs_pi * sizeof(int);  // ~4.85 MB
    int chunk = (int)(avail / per_img);
    if (chunk < 1) chunk = 1;
    if (chunk > NB_TOTAL) chunk = NB_TOTAL;

    u64* fT = (u64*)base;
    u64* fP = fT + (size_t)chunk * wpi;
    u64* sT = fP + (size_t)chunk * wpi;
    u64* sP = sT + (size_t)chunk * wpi;
    int* prT = (int*)(sP + (size_t)chunk * wpi);
    int* prP = prT + (size_t)chunk * wpi;
    int* parentT = prP + (size_t)chunk * wpi;
    int* parentP = parentT + (size_t)chunk * runs_pi;

    k_zero<<<NBLK / NTHR, NTHR, 0, stream>>>(part);

    for (int b0 = 0; b0 < NB_TOTAL; b0 += chunk) {
        int nb = (b0 + chunk <= NB_TOTAL) ? chunk : (NB_TOTAL - b0);
        int npx = nb * IMGPIX;
        long gbase = (long)b0 * IMGPIX;
        int nrows = nb * HH;
        int ninit = (int)(nb * runs_pi);
        int nlf = 2 * nrows * WPR;

        k_maskinit<<<NBLK, NTHR, 0, stream>>>(preds, targets, gbase, npx, fT, fP,
                                              parentT, parentP, ninit);
        k_rows<<<(nrows + NTHR - 1) / NTHR, NTHR, 0, stream>>>(fT, fP, sT, sP, prT, prP, nrows);
        k_link<<<(nlf + NTHR - 1) / NTHR, NTHR, 0, stream>>>(fT, fP, sT, sP, prT, prP,
                                                             parentT, parentP, nrows);
        k_flagup<<<(nlf + NTHR - 1) / NTHR, NTHR, 0, stream>>>(fT, fP, sT, sP, prT, prP,
                                                               parentT, parentP, nrows);
        k_compress<<<NBLK, NTHR, 0, stream>>>(parentT, parentP, ninit);
        k_accum<<<NBLK, NTHR, 0, stream>>>(preds, targets, gbase, npx >> 2,
                                           fT, fP, sT, sP, prT, prP,
                                           parentT, parentP, part);
    }

    double inv_n = 1.0 / ((double)NB_TOTAL * (double)IMGPIX);
    k_final<<<1, NTHR, 0, stream>>>(part, out, inv_n);
}